// Round 5
// baseline (493.522 us; speedup 1.0000x reference)
//
#include <hip/hip_runtime.h>

// GeometricEmbedding, R5: decisive split.
//   k1 (1 thread/pair): gathers (packed R4), d computation, DPP segmented
//       prefix scan -> chi atomics, and writes d_bc[p] (12.8 MB coalesced).
//       No rbf stores, no broadcast phase.
//   k2 (8 threads/pair): reads d_bc[p] (8 lanes share one dword -> L1
//       broadcast), 4 exp2, ONE dense nontemporal float4 store per lane
//       (each wave store instr = 1 KB fully contiguous). No gathers, no
//       shuffles, no masks (mask pre-folded: d_bc=1e30 -> exp2(-inf)=+0).
//       ~22 instrs per KB stored -> should run at write BW (~65-80 us).
//
// Rationale: R0/R3/R4 all land ~210-226 us vs 72 us floor, insensitive to
// LDS ops, gather width, NT hints. The shared structure was the monolithic
// wave mixing gather-latency, broadcast, exp2 and stores in one dependency
// web. This split is also the ablation: if k2 isn't ~write-BW, the store
// path itself is the culprit (next round targets it directly).
// NOT R1's failed split: R1's rbf kernel redid the random-gather front-end
// 8x redundantly; k2 here reads a dense precomputed d array.

#define NRBF 32
constexpr float R_CUT   = 5.0f;
constexpr float WIDTH   = R_CUT / NRBF;            // 0.15625
constexpr float INV_W   = 1.0f / WIDTH;            // 6.4
constexpr float CSPACE  = R_CUT / (NRBF - 1);      // linspace(0,5,32) spacing
constexpr float PI_F    = 3.14159265358979323846f;
constexpr float LOG2E   = 1.44269504088896340736f;
// exp(-0.5*((d-c)/W)^2) == exp2(A*(d-c)^2), A = -0.5*log2(e)/W^2
constexpr float EXP2_A  = -0.5f * LOG2E * INV_W * INV_W;
constexpr float C1  = 0.48860251190291992f;        // sqrt(3/(4pi))
constexpr float C2A = 1.09254843059207907f;        // 0.5*sqrt(15/pi)
constexpr float C2B = 0.31539156525252005f;        // 0.25*sqrt(5/pi)
constexpr float C2C = 0.54627421529603953f;        // 0.25*sqrt(15/pi)

// DPP controls (gfx9/CDNA encoding)
#define DPP_ROW_SHR(n)  (0x110 + (n))
#define DPP_ROW_BCAST15 0x142
#define DPP_ROW_BCAST31 0x143

typedef float f32x4 __attribute__((ext_vector_type(4)));

template <int CTRL>
__device__ __forceinline__ float fdpp0(float x) {
    // bound_ctrl=true: out-of-pattern lanes read 0
    return __int_as_float(__builtin_amdgcn_update_dpp(
        0, __float_as_int(x), CTRL, 0xF, 0xF, true));
}

// ---------------------------------------------------------------------------
// pack kernel: R [n,3] -> R4 [n,4] (16B-aligned gathers for k1)
// ---------------------------------------------------------------------------
__global__ __launch_bounds__(256) void pack_kernel(
    const float* __restrict__ R, float4* __restrict__ R4, int n)
{
    const int t = blockIdx.x * blockDim.x + threadIdx.x;
    if (t < n) R4[t] = make_float4(R[3*t+0], R[3*t+1], R[3*t+2], 0.0f);
}

// ---------------------------------------------------------------------------
// k1: per-pair front-end. d_bc -> d_ws, chi via DPP segmented scan + atomics.
// ---------------------------------------------------------------------------
__global__ __launch_bounds__(256) void dist_chi_kernel(
    const float4* __restrict__ R4,
    const float*  __restrict__ pair_mask,
    const float*  __restrict__ point_mask,
    const int*    __restrict__ idx_i,
    const int*    __restrict__ idx_j,
    float* __restrict__ d_arr,
    float* __restrict__ chi_out,
    int n_pairs)
{
    const int p    = blockIdx.x * blockDim.x + threadIdx.x;
    const int lane = threadIdx.x & 63;

    int   seg = -1;            // idx_i value; -1 for inactive lanes
    float w[8];
    #pragma unroll
    for (int c = 0; c < 8; ++c) w[c] = 0.0f;

    if (p < n_pairs) {
        // read-once streams: nontemporal to avoid polluting L2
        const int   i = __builtin_nontemporal_load(idx_i + p);
        const int   j = __builtin_nontemporal_load(idx_j + p);
        const float m = __builtin_nontemporal_load(pair_mask + p);
        seg = i;

        const float4 qj = R4[j];           // one aligned dwordx4 per endpoint
        const float4 qi = R4[i];           // i-side: sorted -> mostly L1-hit

        const float rx = (qj.x - qi.x) * m;
        const float ry = (qj.y - qi.y) * m;
        const float rz = (qj.z - qi.z) * m;

        const float sq = rx*rx + ry*ry + rz*rz;
        const float d  = sqrtf(sq) * m;    // sqrtf(0)==0 matches ref zero-guard

        // masks are {0,1}: m==0 -> 1e30 -> exp2(-inf)=+0 in k2, bit-exact
        // with ref's exp(..)*0. (Fractional masks would deviate.)
        const float d_bc = (m != 0.0f) ? d : 1e30f;
        __builtin_nontemporal_store(d_bc, d_arr + p);   // coalesced stream

        // --- cutoff envelope ---
        float phi = 0.5f * (__cosf(PI_F * d * (1.0f/R_CUT)) + 1.0f);
        phi *= (d < R_CUT) ? 1.0f : 0.0f;
        phi *= m;

        // --- unit vector (ref: 0 when d==0) ---
        const float inv_d = (d != 0.0f) ? (1.0f / d) : 0.0f;
        const float ux = rx * inv_d * m;
        const float uy = ry * inv_d * m;
        const float uz = rz * inv_d * m;

        float s[8];
        s[0] = C1  * uy;
        s[1] = C1  * uz;
        s[2] = C1  * ux;
        s[3] = C2A * ux * uy;
        s[4] = C2A * uy * uz;
        s[5] = C2B * (3.0f * uz * uz - 1.0f) * m;  // not zero-guarded in ref
        s[6] = C2A * ux * uz;
        s[7] = C2C * (ux * ux - uy * uy);

        const float scale = phi * point_mask[i];   // LAMBDA == 1
        #pragma unroll
        for (int c = 0; c < 8; ++c) w[c] = s[c] * scale;
    }

    // --- segmented reduction: DPP inclusive segmented prefix scan (VALU) ---
    {
        const int prev_seg = __shfl_up(seg, 1, 64);              // 1 bpermute
        const bool head = (lane == 0) || (prev_seg != seg);
        const unsigned long long H = __ballot(head);
        const unsigned long long below = (2ull << lane) - 1ull;  // bits [0..lane]
        const int s = 63 - __clzll(H & below);                   // segment start

        {
            const bool ok = (lane - 1) >= s;
            #pragma unroll
            for (int c = 0; c < 8; ++c) { float t = fdpp0<DPP_ROW_SHR(1)>(w[c]); if (ok) w[c] += t; }
        }
        {
            const bool ok = (lane - 2) >= s;
            #pragma unroll
            for (int c = 0; c < 8; ++c) { float t = fdpp0<DPP_ROW_SHR(2)>(w[c]); if (ok) w[c] += t; }
        }
        {
            const bool ok = (lane - 4) >= s;
            #pragma unroll
            for (int c = 0; c < 8; ++c) { float t = fdpp0<DPP_ROW_SHR(4)>(w[c]); if (ok) w[c] += t; }
        }
        {
            const bool ok = (lane - 8) >= s;
            #pragma unroll
            for (int c = 0; c < 8; ++c) { float t = fdpp0<DPP_ROW_SHR(8)>(w[c]); if (ok) w[c] += t; }
        }
        {   // lane15 -> row1, lane47 -> row3 (odd 16-rows only)
            const bool ok = ((lane >> 4) & 1) && (s < (lane & ~15));
            #pragma unroll
            for (int c = 0; c < 8; ++c) { float t = fdpp0<DPP_ROW_BCAST15>(w[c]); if (ok) w[c] += t; }
        }
        {   // lane31 -> lanes 32..63
            const bool ok = (lane >= 32) && (s < 32);
            #pragma unroll
            for (int c = 0; c < 8; ++c) { float t = fdpp0<DPP_ROW_BCAST31>(w[c]); if (ok) w[c] += t; }
        }

        // tail lanes hold full segment sums (prefix scan)
        const bool tail = (lane == 63) || (((H >> 1) >> lane) & 1ull);
        if (tail && seg >= 0) {
            float* dst = chi_out + (size_t)seg * 8;
            #pragma unroll
            for (int c = 0; c < 8; ++c) unsafeAtomicAdd(dst + c, w[c]);
        }
    }
}

// ---------------------------------------------------------------------------
// k2: pure rbf stream. 8 threads/pair; each wave store instr = dense 1 KB.
// ---------------------------------------------------------------------------
__global__ __launch_bounds__(256) void rbf_stream_kernel(
    const float* __restrict__ d_arr,
    float*       __restrict__ rbf_out,
    int n_pairs)
{
    const int t   = blockIdx.x * blockDim.x + threadIdx.x;
    const int p   = t >> 3;
    const int sub = t & 7;
    if (p >= n_pairs) return;

    const float dd   = d_arr[p];        // 8 lanes share one dword (L1 bcast)
    const float base = dd - (float)(4 * sub) * CSPACE;
    const float a0 = base;
    const float a1 = base - CSPACE;
    const float a2 = base - 2.0f * CSPACE;
    const float a3 = base - 3.0f * CSPACE;

    f32x4 v;
    v.x = __builtin_amdgcn_exp2f(EXP2_A * a0 * a0);
    v.y = __builtin_amdgcn_exp2f(EXP2_A * a1 * a1);
    v.z = __builtin_amdgcn_exp2f(EXP2_A * a2 * a2);
    v.w = __builtin_amdgcn_exp2f(EXP2_A * a3 * a3);

    __builtin_nontemporal_store(
        v, (f32x4*)(rbf_out + (size_t)p * NRBF + 4 * sub));
}

extern "C" void kernel_launch(void* const* d_in, const int* in_sizes, int n_in,
                              void* d_out, int out_size, void* d_ws, size_t ws_size,
                              hipStream_t stream) {
    const float* R          = (const float*)d_in[0];
    const float* pair_mask  = (const float*)d_in[1];
    const float* point_mask = (const float*)d_in[2];
    const int*   idx_i      = (const int*)d_in[3];
    const int*   idx_j      = (const int*)d_in[4];
    // d_in[5] = z (unused by reference outputs)

    const int n_pairs = in_sizes[1];   // pair_mask length
    const int n       = in_sizes[2];   // point_mask length

    float* rbf_out = (float*)d_out;                       // [n_pairs, 32]
    float* chi_out = rbf_out + (size_t)n_pairs * NRBF;    // [n, 8]

    // harness poisons d_out (and ws) with 0xAA before every timed launch
    hipMemsetAsync(chi_out, 0, (size_t)n * 8 * sizeof(float), stream);

    const int block = 256;

    // workspace layout: R4 [n,4] floats, then d_bc [n_pairs] floats
    float4* R4    = (float4*)d_ws;
    float*  d_arr = (float*)d_ws + (size_t)n * 4;

    pack_kernel<<<(n + block - 1) / block, block, 0, stream>>>(R, R4, n);

    dist_chi_kernel<<<(n_pairs + block - 1) / block, block, 0, stream>>>(
        R4, pair_mask, point_mask, idx_i, idx_j, d_arr, chi_out, n_pairs);

    {
        const long long tot = (long long)n_pairs * 8;
        const int grid = (int)((tot + block - 1) / block);
        rbf_stream_kernel<<<grid, block, 0, stream>>>(d_arr, rbf_out, n_pairs);
    }
}